// Round 1
// baseline (62.406 us; speedup 1.0000x reference)
//
#include <hip/hip_runtime.h>
#include <math.h>

#define NT 100     // NUM_TOPICS
#define VOCAB 8192
#define TOPN 20

// ---------------- zero col_cnt ----------------
__global__ __launch_bounds__(256) void zero_kernel(int* __restrict__ col_cnt) {
    int i = blockIdx.x * 256 + threadIdx.x;
    if (i < VOCAB) col_cnt[i] = 0;
}

// ---------------- per-topic top-20 + softmax stats ----------------
__global__ __launch_bounds__(256) void topk_kernel(
    const float* __restrict__ beta,
    int*   __restrict__ col_cnt,
    int*   __restrict__ top_idx,   // [NT][TOPN]
    float* __restrict__ top_p,     // [NT][TOPN]
    float* __restrict__ rowstats)  // [NT][2] = {rowmax, full sumexp}
{
    const int k = blockIdx.x;
    const int t = threadIdx.x;

    __shared__ float srow[VOCAB];          // 32 KB
    __shared__ float s_wv[4];
    __shared__ int   s_wi[4];
    __shared__ float s_winval[TOPN];
    __shared__ int   s_winidx[TOPN];
    __shared__ float s_bcast;

    const float* row = beta + (size_t)k * VOCAB;
#pragma unroll
    for (int i = 0; i < VOCAB / 256; ++i)
        srow[i * 256 + t] = row[i * 256 + t];
    __syncthreads();

    // 20 iterative block-argmax extractions (destructive in LDS)
    for (int it = 0; it < TOPN; ++it) {
        float bv = -INFINITY;
        int   bi = 0x7fffffff;
#pragma unroll
        for (int i = 0; i < VOCAB / 256; ++i) {
            const int idx = i * 256 + t;
            const float v = srow[idx];
            if (v > bv) { bv = v; bi = idx; }   // idx increases with i -> ties keep smallest
        }
        // wave (64-lane) argmax reduce
#pragma unroll
        for (int off = 32; off >= 1; off >>= 1) {
            const float ov = __shfl_down(bv, off);
            const int   oi = __shfl_down(bi, off);
            if (ov > bv || (ov == bv && oi < bi)) { bv = ov; bi = oi; }
        }
        if ((t & 63) == 0) { s_wv[t >> 6] = bv; s_wi[t >> 6] = bi; }
        __syncthreads();
        if (t == 0) {
            float mv = s_wv[0]; int mi = s_wi[0];
#pragma unroll
            for (int w = 1; w < 4; ++w)
                if (s_wv[w] > mv || (s_wv[w] == mv && s_wi[w] < mi)) { mv = s_wv[w]; mi = s_wi[w]; }
            s_winval[it] = mv;
            s_winidx[it] = mi;
            srow[mi] = -INFINITY;              // destroy winner
        }
        __syncthreads();
    }

    const float rowmax = s_winval[0];

    // full-row sumexp: destroyed entries give exp(-inf)=0; add winners back
    float part = 0.f;
#pragma unroll
    for (int i = 0; i < VOCAB / 256; ++i)
        part += expf(srow[i * 256 + t] - rowmax);
#pragma unroll
    for (int off = 32; off >= 1; off >>= 1)
        part += __shfl_down(part, off);
    if ((t & 63) == 0) s_wv[t >> 6] = part;
    __syncthreads();
    if (t == 0) {
        float s = s_wv[0] + s_wv[1] + s_wv[2] + s_wv[3];
        float ps = 0.f;
        for (int j = 0; j < TOPN; ++j) {
            const float e = expf(s_winval[j] - rowmax);
            ps += e;
            s  += e;
        }
        rowstats[k * 2 + 0] = rowmax;
        rowstats[k * 2 + 1] = s;
        s_bcast = ps;                          // top-20 softmax denom
    }
    __syncthreads();
    if (t < TOPN) {
        const int idx = s_winidx[t];
        top_p[k * TOPN + t]   = expf(s_winval[t] - rowmax) / s_bcast;
        top_idx[k * TOPN + t] = idx;
        atomicAdd(&col_cnt[idx], 1);
    }
}

// ---------------- M = p@W (gather), min/max, fused loss ----------------
__global__ __launch_bounds__(1024) void main_kernel(
    const float* __restrict__ beta,
    const float* __restrict__ W,
    const int*   __restrict__ col_cnt,
    const int*   __restrict__ top_idx,
    const float* __restrict__ top_p,
    const float* __restrict__ rowstats,
    float* __restrict__ posk,   // [NT]
    float* __restrict__ negk)   // [NT]
{
    const int k = blockIdx.x;
    const int t = threadIdx.x;

    __shared__ float sM[VOCAB];            // 32 KB
    __shared__ int   sIdx[TOPN];
    __shared__ float sP[TOPN];
    __shared__ float sredA[16], sredB[16];
    __shared__ float s_mn, s_mx;

    if (t < TOPN) { sIdx[t] = top_idx[k * TOPN + t]; sP[t] = top_p[k * TOPN + t]; }
    __syncthreads();

    // registers copies (compile-time indexed only)
    int   idx_r[TOPN];
    float p_r[TOPN];
#pragma unroll
    for (int j = 0; j < TOPN; ++j) { idx_r[j] = sIdx[j]; p_r[j] = sP[j]; }

    float mn = INFINITY, mx = -INFINITY;
#pragma unroll
    for (int i = 0; i < VOCAB / (1024 * 4); ++i) {   // 2 iters
        const int v = (i * 1024 + t) * 4;
        float4 m = make_float4(0.f, 0.f, 0.f, 0.f);
#pragma unroll
        for (int j = 0; j < TOPN; ++j) {
            const float4 w = *reinterpret_cast<const float4*>(W + (size_t)idx_r[j] * VOCAB + v);
            const float pj = p_r[j];
            m.x += pj * w.x; m.y += pj * w.y; m.z += pj * w.z; m.w += pj * w.w;
        }
        *reinterpret_cast<float4*>(sM + v) = m;
        mn = fminf(mn, fminf(fminf(m.x, m.y), fminf(m.z, m.w)));
        mx = fmaxf(mx, fmaxf(fmaxf(m.x, m.y), fmaxf(m.z, m.w)));
    }

    // block min/max reduce (16 waves)
#pragma unroll
    for (int off = 32; off >= 1; off >>= 1) {
        mn = fminf(mn, __shfl_down(mn, off));
        mx = fmaxf(mx, __shfl_down(mx, off));
    }
    if ((t & 63) == 0) { sredA[t >> 6] = mn; sredB[t >> 6] = mx; }
    __syncthreads();
    if (t == 0) {
        float a = sredA[0], b = sredB[0];
        for (int w = 1; w < 16; ++w) { a = fminf(a, sredA[w]); b = fmaxf(b, sredB[w]); }
        s_mn = a; s_mx = b;
    }
    __syncthreads();

    const float mmin = s_mn;
    const float inv  = 1.0f / (s_mx - mmin);
    const float rmax = rowstats[k * 2 + 0];
    const float rinv = 1.0f / rowstats[k * 2 + 1];

    float pos = 0.f, neg = 0.f;
#pragma unroll
    for (int i = 0; i < VOCAB / 1024; ++i) {         // 8 iters
        const int v = i * 1024 + t;
        const float Wc = 1.0f - (sM[v] - mmin) * inv;
        const float sb = expf(beta[(size_t)k * VOCAB + v] - rmax) * rinv;
        const float l  = 100.f * sb * sb * Wc;
        int is_top = 0;
#pragma unroll
        for (int j = 0; j < TOPN; ++j) is_top |= (idx_r[j] == v) ? 1 : 0;
        const bool md = (col_cnt[v] - is_top) > 0;
        if (md) pos += l; else neg += l;
    }
#pragma unroll
    for (int off = 32; off >= 1; off >>= 1) {
        pos += __shfl_down(pos, off);
        neg += __shfl_down(neg, off);
    }
    if ((t & 63) == 0) { sredA[t >> 6] = pos; sredB[t >> 6] = neg; }
    __syncthreads();
    if (t == 0) {
        float a = 0.f, b = 0.f;
        for (int w = 0; w < 16; ++w) { a += sredA[w]; b += sredB[w]; }
        posk[k] = a;
        negk[k] = b;
    }
}

// ---------------- deterministic scalar finalize ----------------
__global__ void finalize_kernel(const float* __restrict__ posk,
                                const float* __restrict__ negk,
                                const int*   __restrict__ epoch,
                                float* __restrict__ out)
{
    if (threadIdx.x == 0 && blockIdx.x == 0) {
        float pos = 0.f, neg = 0.f;
        for (int i = 0; i < NT; ++i) { pos += posk[i]; neg += negk[i]; }
        const float total = (pos * 0.7f + neg * 0.3f) * 2.0f;
        const int e = *epoch;
        const float la = (e < 100) ? (float)e : 100.0f;   // lambda_a_delta = 100/100 = 1
        *out = la * total;
    }
}

extern "C" void kernel_launch(void* const* d_in, const int* in_sizes, int n_in,
                              void* d_out, int out_size, void* d_ws, size_t ws_size,
                              hipStream_t stream)
{
    (void)in_sizes; (void)n_in; (void)out_size; (void)ws_size;
    const float* beta  = (const float*)d_in[0];
    const float* W     = (const float*)d_in[1];
    const int*   epoch = (const int*)d_in[2];
    float* out = (float*)d_out;

    char* ws = (char*)d_ws;
    int*   col_cnt  = (int*)ws;    ws += VOCAB * sizeof(int);
    int*   top_idx  = (int*)ws;    ws += NT * TOPN * sizeof(int);
    float* top_p    = (float*)ws;  ws += NT * TOPN * sizeof(float);
    float* rowstats = (float*)ws;  ws += NT * 2 * sizeof(float);
    float* posk     = (float*)ws;  ws += NT * sizeof(float);
    float* negk     = (float*)ws;  ws += NT * sizeof(float);

    zero_kernel<<<(VOCAB + 255) / 256, 256, 0, stream>>>(col_cnt);
    topk_kernel<<<NT, 256, 0, stream>>>(beta, col_cnt, top_idx, top_p, rowstats);
    main_kernel<<<NT, 1024, 0, stream>>>(beta, W, col_cnt, top_idx, top_p, rowstats, posk, negk);
    finalize_kernel<<<1, 64, 0, stream>>>(posk, negk, epoch, out);
}

// Round 2
// 56.592 us; speedup vs baseline: 1.1027x; 1.1027x over previous
//
#include <hip/hip_runtime.h>
#include <math.h>

#define NT 100       // NUM_TOPICS
#define VOCAB 8192
#define TOPN 20
#define CHUNKS 8
#define CCOLS (VOCAB / CHUNKS)   // 1024
#define CAP 4096

// ---------------- per-topic top-20 via threshold filter ----------------
__global__ __launch_bounds__(256) void topk_kernel(
    const float* __restrict__ beta,
    int*   __restrict__ top_idx,   // [NT][TOPN]
    float* __restrict__ top_p,     // [NT][TOPN]
    float* __restrict__ rowstats)  // [NT][2] = {rowmax, full sumexp}
{
    const int k = blockIdx.x;
    const int t = threadIdx.x;

    __shared__ float srow[VOCAB];            // 32 KB
    __shared__ float sred[4];
    __shared__ int   sredi[4];
    __shared__ float s_T;
    __shared__ int   s_base;
    __shared__ float cu[CAP];                // 16 KB candidate values
    __shared__ unsigned short ci[CAP];       // 8 KB candidate indices
    __shared__ float s_winv[TOPN];
    __shared__ int   s_wini[TOPN];
    __shared__ float s_ps;

    const float* row = beta + (size_t)k * VOCAB;

    // load row -> LDS (float4), block max
    float mx = -INFINITY;
#pragma unroll
    for (int i = 0; i < VOCAB / (256 * 4); ++i) {     // 8 iters
        float4 v = *reinterpret_cast<const float4*>(row + (size_t)(i * 256 + t) * 4);
        reinterpret_cast<float4*>(srow)[i * 256 + t] = v;
        mx = fmaxf(mx, fmaxf(fmaxf(v.x, v.y), fmaxf(v.z, v.w)));
    }
#pragma unroll
    for (int off = 32; off >= 1; off >>= 1) mx = fmaxf(mx, __shfl_down(mx, off));
    if ((t & 63) == 0) sred[t >> 6] = mx;
    __syncthreads();
    const float rowmax = fmaxf(fmaxf(sred[0], sred[1]), fmaxf(sred[2], sred[3]));

    // find threshold T with count(>=T) >= TOPN  (1 iteration for N(0,1) data)
    float T = rowmax - 2.0f;
    for (int guard = 0; guard < 64; ++guard) {
        int c = 0;
#pragma unroll
        for (int i = 0; i < VOCAB / 256; ++i) c += (srow[i * 256 + t] >= T) ? 1 : 0;
#pragma unroll
        for (int off = 32; off >= 1; off >>= 1) c += __shfl_down(c, off);
        if ((t & 63) == 0) sredi[t >> 6] = c;
        __syncthreads();
        const int cnt = sredi[0] + sredi[1] + sredi[2] + sredi[3];
        if (cnt >= TOPN) { if (t == 0) s_T = T; break; }
        T -= 0.5f;
        __syncthreads();
    }
    if (t == 0) s_base = 0;
    __syncthreads();
    T = s_T;

    // ballot-compact candidates into cu/ci
#pragma unroll
    for (int i = 0; i < VOCAB / 256; ++i) {
        const int idx = i * 256 + t;
        const float v = srow[idx];
        const bool pr = (v >= T);
        const unsigned long long mask = __ballot(pr);
        const int lane = t & 63;
        const int pre = __popcll(mask & ((1ull << lane) - 1ull));
        const int nb  = __popcll(mask);
        int base = 0;
        if (lane == 0 && nb) base = atomicAdd(&s_base, nb);
        base = __shfl(base, 0);
        if (pr) {
            const int p = base + pre;
            if (p < CAP) { cu[p] = v; ci[p] = (unsigned short)idx; }
        }
    }
    __syncthreads();
    const int ncand = min(s_base, CAP);

    // 20 extractions, single wave over candidate list
    if (t < 64) {
        for (int it = 0; it < TOPN; ++it) {
            float bv = -INFINITY; int bp = -1;
            for (int p = t; p < ncand; p += 64) {
                const float v = cu[p];
                if (v > bv) { bv = v; bp = p; }
            }
#pragma unroll
            for (int off = 32; off >= 1; off >>= 1) {
                const float ov = __shfl_down(bv, off);
                const int   op = __shfl_down(bp, off);
                if (ov > bv) { bv = ov; bp = op; }
            }
            bp = __shfl(bp, 0);
            bv = __shfl(bv, 0);
            if (t == 0) { s_winv[it] = bv; s_wini[it] = ci[bp]; }
            cu[bp] = -INFINITY;   // all lanes write same value to same addr
        }
    }
    __syncthreads();

    // top-20 softmax denom
    if (t == 0) {
        float ps = 0.f;
#pragma unroll
        for (int j = 0; j < TOPN; ++j) ps += expf(s_winv[j] - rowmax);
        s_ps = ps;
    }
    __syncthreads();
    if (t < TOPN) {
        top_idx[k * TOPN + t] = s_wini[t];
        top_p[k * TOPN + t]   = expf(s_winv[t] - rowmax) / s_ps;
    }

    // full-row sumexp (srow intact)
    float se = 0.f;
#pragma unroll
    for (int i = 0; i < VOCAB / 256; ++i) se += expf(srow[i * 256 + t] - rowmax);
#pragma unroll
    for (int off = 32; off >= 1; off >>= 1) se += __shfl_down(se, off);
    if ((t & 63) == 0) sred[t >> 6] = se;
    __syncthreads();
    if (t == 0) {
        rowstats[2 * k + 0] = rowmax;
        rowstats[2 * k + 1] = sred[0] + sred[1] + sred[2] + sred[3];
    }
}

// ---------------- M = p@W gather, chunked: grid NT*CHUNKS ----------------
__global__ __launch_bounds__(256) void mcompute_kernel(
    const float* __restrict__ W,
    const int*   __restrict__ top_idx,
    const float* __restrict__ top_p,
    float* __restrict__ M,        // [NT][VOCAB]
    float* __restrict__ mmpart)   // [NT][CHUNKS][2] = {min,max}
{
    const int b = blockIdx.x;
    const int k = b / CHUNKS;
    const int c = b % CHUNKS;
    const int t = threadIdx.x;

    __shared__ int   sIdx[TOPN];
    __shared__ float sP[TOPN];
    __shared__ float sA[4], sB[4];
    if (t < TOPN) { sIdx[t] = top_idx[k * TOPN + t]; sP[t] = top_p[k * TOPN + t]; }
    __syncthreads();

    int   idx_r[TOPN];
    float p_r[TOPN];
#pragma unroll
    for (int j = 0; j < TOPN; ++j) { idx_r[j] = sIdx[j]; p_r[j] = sP[j]; }

    const int col = c * CCOLS + t * 4;     // 256 threads * float4 = 1024 cols
    float4 m = make_float4(0.f, 0.f, 0.f, 0.f);
#pragma unroll
    for (int j = 0; j < TOPN; ++j) {
        const float4 w = *reinterpret_cast<const float4*>(W + (size_t)idx_r[j] * VOCAB + col);
        const float pj = p_r[j];
        m.x += pj * w.x; m.y += pj * w.y; m.z += pj * w.z; m.w += pj * w.w;
    }
    *reinterpret_cast<float4*>(M + (size_t)k * VOCAB + col) = m;

    float mn = fminf(fminf(m.x, m.y), fminf(m.z, m.w));
    float mxv = fmaxf(fmaxf(m.x, m.y), fmaxf(m.z, m.w));
#pragma unroll
    for (int off = 32; off >= 1; off >>= 1) {
        mn  = fminf(mn,  __shfl_down(mn,  off));
        mxv = fmaxf(mxv, __shfl_down(mxv, off));
    }
    if ((t & 63) == 0) { sA[t >> 6] = mn; sB[t >> 6] = mxv; }
    __syncthreads();
    if (t == 0) {
        mmpart[(k * CHUNKS + c) * 2 + 0] = fminf(fminf(sA[0], sA[1]), fminf(sA[2], sA[3]));
        mmpart[(k * CHUNKS + c) * 2 + 1] = fmaxf(fmaxf(sB[0], sB[1]), fmaxf(sB[2], sB[3]));
    }
}

// ---------------- loss: LDS col-count + fused Wc/softmax^2 ----------------
__global__ __launch_bounds__(1024) void loss_kernel(
    const float* __restrict__ beta,
    const float* __restrict__ M,
    const int*   __restrict__ top_idx,
    const float* __restrict__ rowstats,
    const float* __restrict__ mmpart,
    float* __restrict__ posk,
    float* __restrict__ negk)
{
    const int k = blockIdx.x;
    const int t = threadIdx.x;

    __shared__ int cnt[VOCAB];               // 32 KB
    __shared__ float sredA[16], sredB[16];
    __shared__ float s_mn, s_mx;

#pragma unroll
    for (int i = 0; i < VOCAB / 1024; ++i) cnt[i * 1024 + t] = 0;
    __syncthreads();

    for (int e = t; e < NT * TOPN; e += 1024) atomicAdd(&cnt[top_idx[e]], 1);
    __syncthreads();
    if (t < TOPN) atomicSub(&cnt[top_idx[k * TOPN + t]], 1);   // remove own topic
    if (t == 0) {
        float mn = INFINITY, mxv = -INFINITY;
        for (int c = 0; c < CHUNKS; ++c) {
            mn  = fminf(mn,  mmpart[(k * CHUNKS + c) * 2 + 0]);
            mxv = fmaxf(mxv, mmpart[(k * CHUNKS + c) * 2 + 1]);
        }
        s_mn = mn; s_mx = mxv;
    }
    __syncthreads();

    const float mmin = s_mn;
    const float inv  = 1.0f / (s_mx - mmin);
    const float rmax = rowstats[2 * k + 0];
    const float rinv = 1.0f / rowstats[2 * k + 1];

    float pos = 0.f, neg = 0.f;
#pragma unroll
    for (int i = 0; i < VOCAB / (1024 * 4); ++i) {     // 2 iters
        const int v = (i * 1024 + t) * 4;
        const float4 m = *reinterpret_cast<const float4*>(M + (size_t)k * VOCAB + v);
        const float4 b = *reinterpret_cast<const float4*>(beta + (size_t)k * VOCAB + v);
        {
            const float Wc = 1.0f - (m.x - mmin) * inv;
            const float sb = expf(b.x - rmax) * rinv;
            const float l  = 100.f * sb * sb * Wc;
            if (cnt[v + 0] > 0) pos += l; else neg += l;
        }
        {
            const float Wc = 1.0f - (m.y - mmin) * inv;
            const float sb = expf(b.y - rmax) * rinv;
            const float l  = 100.f * sb * sb * Wc;
            if (cnt[v + 1] > 0) pos += l; else neg += l;
        }
        {
            const float Wc = 1.0f - (m.z - mmin) * inv;
            const float sb = expf(b.z - rmax) * rinv;
            const float l  = 100.f * sb * sb * Wc;
            if (cnt[v + 2] > 0) pos += l; else neg += l;
        }
        {
            const float Wc = 1.0f - (m.w - mmin) * inv;
            const float sb = expf(b.w - rmax) * rinv;
            const float l  = 100.f * sb * sb * Wc;
            if (cnt[v + 3] > 0) pos += l; else neg += l;
        }
    }
#pragma unroll
    for (int off = 32; off >= 1; off >>= 1) {
        pos += __shfl_down(pos, off);
        neg += __shfl_down(neg, off);
    }
    if ((t & 63) == 0) { sredA[t >> 6] = pos; sredB[t >> 6] = neg; }
    __syncthreads();
    if (t == 0) {
        float a = 0.f, b2 = 0.f;
        for (int w = 0; w < 16; ++w) { a += sredA[w]; b2 += sredB[w]; }
        posk[k] = a;
        negk[k] = b2;
    }
}

// ---------------- deterministic scalar finalize ----------------
__global__ void finalize_kernel(const float* __restrict__ posk,
                                const float* __restrict__ negk,
                                const int*   __restrict__ epoch,
                                float* __restrict__ out)
{
    if (threadIdx.x == 0 && blockIdx.x == 0) {
        float pos = 0.f, neg = 0.f;
        for (int i = 0; i < NT; ++i) { pos += posk[i]; neg += negk[i]; }
        const float total = (pos * 0.7f + neg * 0.3f) * 2.0f;
        const int e = *epoch;
        const float la = (e < 100) ? (float)e : 100.0f;   // lambda_a_delta = 1
        *out = la * total;
    }
}

extern "C" void kernel_launch(void* const* d_in, const int* in_sizes, int n_in,
                              void* d_out, int out_size, void* d_ws, size_t ws_size,
                              hipStream_t stream)
{
    (void)in_sizes; (void)n_in; (void)out_size; (void)ws_size;
    const float* beta  = (const float*)d_in[0];
    const float* W     = (const float*)d_in[1];
    const int*   epoch = (const int*)d_in[2];
    float* out = (float*)d_out;

    char* ws = (char*)d_ws;
    int*   top_idx  = (int*)ws;    ws += NT * TOPN * sizeof(int);
    float* top_p    = (float*)ws;  ws += NT * TOPN * sizeof(float);
    float* rowstats = (float*)ws;  ws += NT * 2 * sizeof(float);
    float* mmpart   = (float*)ws;  ws += NT * CHUNKS * 2 * sizeof(float);
    float* posk     = (float*)ws;  ws += NT * sizeof(float);
    float* negk     = (float*)ws;  ws += NT * sizeof(float);
    ws = (char*)(((size_t)ws + 255) & ~(size_t)255);
    float* M        = (float*)ws;  ws += (size_t)NT * VOCAB * sizeof(float);

    topk_kernel<<<NT, 256, 0, stream>>>(beta, top_idx, top_p, rowstats);
    mcompute_kernel<<<NT * CHUNKS, 256, 0, stream>>>(W, top_idx, top_p, M, mmpart);
    loss_kernel<<<NT, 1024, 0, stream>>>(beta, M, top_idx, rowstats, mmpart, posk, negk);
    finalize_kernel<<<1, 64, 0, stream>>>(posk, negk, epoch, out);
}

// Round 3
// 53.671 us; speedup vs baseline: 1.1628x; 1.0544x over previous
//
#include <hip/hip_runtime.h>
#include <math.h>

#define NT 100       // NUM_TOPICS
#define VOCAB 8192
#define TOPN 20
#define CHUNKS 8
#define CCOLS (VOCAB / CHUNKS)   // 1024
#define CAP 4096

// ---------------- per-topic top-20, register-resident ----------------
__global__ __launch_bounds__(256) void topk_kernel(
    const float* __restrict__ beta,
    int*   __restrict__ top_idx,   // [NT][TOPN]
    float* __restrict__ top_p,     // [NT][TOPN]
    float* __restrict__ rowstats)  // [NT][2] = {rowmax, full sumexp}
{
    const int k = blockIdx.x;
    const int t = threadIdx.x;

    __shared__ float sred[4];
    __shared__ int   sredi[4];
    __shared__ float s_T;
    __shared__ int   s_base;
    __shared__ float cu[CAP];                // candidate values
    __shared__ unsigned short ci[CAP];       // candidate indices
    __shared__ float s_winv[TOPN];
    __shared__ int   s_wini[TOPN];
    __shared__ float s_ps;

    const float* row = beta + (size_t)k * VOCAB;

    // load row into registers (8 x float4 = 32 elems/thread), block max
    float4 r[8];
    float mx = -INFINITY;
#pragma unroll
    for (int i = 0; i < 8; ++i) {
        r[i] = *reinterpret_cast<const float4*>(row + (size_t)(i * 256 + t) * 4);
        mx = fmaxf(mx, fmaxf(fmaxf(r[i].x, r[i].y), fmaxf(r[i].z, r[i].w)));
    }
#pragma unroll
    for (int off = 32; off >= 1; off >>= 1) mx = fmaxf(mx, __shfl_down(mx, off));
    if ((t & 63) == 0) sred[t >> 6] = mx;
    __syncthreads();
    const float rowmax = fmaxf(fmaxf(sred[0], sred[1]), fmaxf(sred[2], sred[3]));

    // threshold T with count(>=T) >= TOPN (1 iter typical for N(0,1))
    float T = rowmax - 2.0f;
    for (int guard = 0; guard < 64; ++guard) {
        int c = 0;
#pragma unroll
        for (int i = 0; i < 8; ++i) {
            c += (r[i].x >= T) ? 1 : 0;
            c += (r[i].y >= T) ? 1 : 0;
            c += (r[i].z >= T) ? 1 : 0;
            c += (r[i].w >= T) ? 1 : 0;
        }
#pragma unroll
        for (int off = 32; off >= 1; off >>= 1) c += __shfl_down(c, off);
        if ((t & 63) == 0) sredi[t >> 6] = c;
        __syncthreads();
        const int cnt = sredi[0] + sredi[1] + sredi[2] + sredi[3];
        if (cnt >= TOPN) { if (t == 0) s_T = T; break; }
        T -= 0.5f;
        __syncthreads();
    }
    if (t == 0) s_base = 0;
    __syncthreads();
    T = s_T;

    // ballot-compact candidates from registers
#pragma unroll
    for (int i = 0; i < 8; ++i) {
#pragma unroll
        for (int e = 0; e < 4; ++e) {
            const float v = (&r[i].x)[e];
            const int idx = (i * 256 + t) * 4 + e;
            const bool pr = (v >= T);
            const unsigned long long mask = __ballot(pr);
            const int lane = t & 63;
            const int pre = __popcll(mask & ((1ull << lane) - 1ull));
            int base = 0;
            if (lane == 0) base = atomicAdd(&s_base, __popcll(mask));
            base = __shfl(base, 0);
            if (pr) {
                const int p = base + pre;
                if (p < CAP) { cu[p] = v; ci[p] = (unsigned short)idx; }
            }
        }
    }
    __syncthreads();
    const int ncand = min(s_base, CAP);

    // 20 extractions, single wave over candidate list
    if (t < 64) {
        for (int it = 0; it < TOPN; ++it) {
            float bv = -INFINITY; int bp = -1;
            for (int p = t; p < ncand; p += 64) {
                const float v = cu[p];
                if (v > bv) { bv = v; bp = p; }
            }
#pragma unroll
            for (int off = 32; off >= 1; off >>= 1) {
                const float ov = __shfl_down(bv, off);
                const int   op = __shfl_down(bp, off);
                if (ov > bv) { bv = ov; bp = op; }
            }
            bp = __shfl(bp, 0);
            bv = __shfl(bv, 0);
            if (t == 0) { s_winv[it] = bv; s_wini[it] = ci[bp]; }
            cu[bp] = -INFINITY;
        }
    }
    __syncthreads();

    // top-20 softmax denom
    if (t == 0) {
        float ps = 0.f;
#pragma unroll
        for (int j = 0; j < TOPN; ++j) ps += expf(s_winv[j] - rowmax);
        s_ps = ps;
    }
    __syncthreads();
    if (t < TOPN) {
        top_idx[k * TOPN + t] = s_wini[t];
        top_p[k * TOPN + t]   = expf(s_winv[t] - rowmax) / s_ps;
    }

    // full-row sumexp from registers
    float se = 0.f;
#pragma unroll
    for (int i = 0; i < 8; ++i) {
        se += expf(r[i].x - rowmax);
        se += expf(r[i].y - rowmax);
        se += expf(r[i].z - rowmax);
        se += expf(r[i].w - rowmax);
    }
#pragma unroll
    for (int off = 32; off >= 1; off >>= 1) se += __shfl_down(se, off);
    if ((t & 63) == 0) sred[t >> 6] = se;
    __syncthreads();
    if (t == 0) {
        rowstats[2 * k + 0] = rowmax;
        rowstats[2 * k + 1] = sred[0] + sred[1] + sred[2] + sred[3];
    }
}

// -------- fused gather + loss partials (M stays in registers) --------
// per (topic k, chunk c): m = sum_j p_j * W[idx_j, chunk cols] in regs;
// emits {min,max} and {A_pos,B_pos,A_neg,B_neg} where A=sum 100 p^2,
// B=sum 100 p^2 * M over the chunk, split by Md membership.
__global__ __launch_bounds__(256) void fused_kernel(
    const float* __restrict__ beta,
    const float* __restrict__ W,
    const int*   __restrict__ top_idx,
    const float* __restrict__ top_p,
    const float* __restrict__ rowstats,
    float* __restrict__ mmpart,   // [NT][CHUNKS][2]
    float* __restrict__ parts)    // [NT][CHUNKS][4]
{
    const int b = blockIdx.x;
    const int k = b / CHUNKS;
    const int c = b % CHUNKS;
    const int t = threadIdx.x;

    __shared__ int   sIdx[TOPN];
    __shared__ float sP[TOPN];
    __shared__ int   cnt[CCOLS];             // 4 KB chunk histogram
    __shared__ float sA[4], sB[4], sC[4], sD[4], sE[4], sF[4];

    if (t < TOPN) { sIdx[t] = top_idx[k * TOPN + t]; sP[t] = top_p[k * TOPN + t]; }
#pragma unroll
    for (int i = 0; i < CCOLS / 256; ++i) cnt[i * 256 + t] = 0;
    __syncthreads();

    // chunk-local column histogram over all topics' top-20
    const int lo = c * CCOLS;
    for (int e = t; e < NT * TOPN; e += 256) {
        const int v = top_idx[e] - lo;
        if ((unsigned)v < (unsigned)CCOLS) atomicAdd(&cnt[v], 1);
    }
    __syncthreads();
    if (t < TOPN) {                           // remove own topic
        const int v = sIdx[t] - lo;
        if ((unsigned)v < (unsigned)CCOLS) atomicSub(&cnt[v], 1);
    }

    int   idx_r[TOPN];
    float p_r[TOPN];
#pragma unroll
    for (int j = 0; j < TOPN; ++j) { idx_r[j] = sIdx[j]; p_r[j] = sP[j]; }

    const int col = lo + t * 4;
    float4 m = make_float4(0.f, 0.f, 0.f, 0.f);
#pragma unroll
    for (int j = 0; j < TOPN; ++j) {
        const float4 w = *reinterpret_cast<const float4*>(W + (size_t)idx_r[j] * VOCAB + col);
        const float pj = p_r[j];
        m.x += pj * w.x; m.y += pj * w.y; m.z += pj * w.z; m.w += pj * w.w;
    }

    float mn  = fminf(fminf(m.x, m.y), fminf(m.z, m.w));
    float mxv = fmaxf(fmaxf(m.x, m.y), fmaxf(m.z, m.w));

    // full softmax weights for this chunk
    const float rmax = rowstats[2 * k + 0];
    const float rinv = 1.0f / rowstats[2 * k + 1];
    const float4 bv = *reinterpret_cast<const float4*>(beta + (size_t)k * VOCAB + col);
    float4 w4;
    w4.x = expf(bv.x - rmax) * rinv;  w4.x = 100.f * w4.x * w4.x;
    w4.y = expf(bv.y - rmax) * rinv;  w4.y = 100.f * w4.y * w4.y;
    w4.z = expf(bv.z - rmax) * rinv;  w4.z = 100.f * w4.z * w4.z;
    w4.w = expf(bv.w - rmax) * rinv;  w4.w = 100.f * w4.w * w4.w;

    __syncthreads();                          // cnt final

    float Apos = 0.f, Bpos = 0.f, Aneg = 0.f, Bneg = 0.f;
    {
        const int lc = t * 4;
        if (cnt[lc + 0] > 0) { Apos += w4.x; Bpos += w4.x * m.x; } else { Aneg += w4.x; Bneg += w4.x * m.x; }
        if (cnt[lc + 1] > 0) { Apos += w4.y; Bpos += w4.y * m.y; } else { Aneg += w4.y; Bneg += w4.y * m.y; }
        if (cnt[lc + 2] > 0) { Apos += w4.z; Bpos += w4.z * m.z; } else { Aneg += w4.z; Bneg += w4.z * m.z; }
        if (cnt[lc + 3] > 0) { Apos += w4.w; Bpos += w4.w * m.w; } else { Aneg += w4.w; Bneg += w4.w * m.w; }
    }

#pragma unroll
    for (int off = 32; off >= 1; off >>= 1) {
        mn   = fminf(mn,  __shfl_down(mn,  off));
        mxv  = fmaxf(mxv, __shfl_down(mxv, off));
        Apos += __shfl_down(Apos, off);
        Bpos += __shfl_down(Bpos, off);
        Aneg += __shfl_down(Aneg, off);
        Bneg += __shfl_down(Bneg, off);
    }
    if ((t & 63) == 0) {
        const int w = t >> 6;
        sA[w] = mn; sB[w] = mxv; sC[w] = Apos; sD[w] = Bpos; sE[w] = Aneg; sF[w] = Bneg;
    }
    __syncthreads();
    if (t == 0) {
        const int o = (k * CHUNKS + c);
        mmpart[o * 2 + 0] = fminf(fminf(sA[0], sA[1]), fminf(sA[2], sA[3]));
        mmpart[o * 2 + 1] = fmaxf(fmaxf(sB[0], sB[1]), fmaxf(sB[2], sB[3]));
        parts[o * 4 + 0] = sC[0] + sC[1] + sC[2] + sC[3];
        parts[o * 4 + 1] = sD[0] + sD[1] + sD[2] + sD[3];
        parts[o * 4 + 2] = sE[0] + sE[1] + sE[2] + sE[3];
        parts[o * 4 + 3] = sF[0] + sF[1] + sF[2] + sF[3];
    }
}

// ---------------- deterministic finalize ----------------
__global__ __launch_bounds__(128) void finalize_kernel(
    const float* __restrict__ mmpart,
    const float* __restrict__ parts,
    const int*   __restrict__ epoch,
    float* __restrict__ out)
{
    const int t = threadIdx.x;
    __shared__ float sp[128], sn[128];
    float pos = 0.f, neg = 0.f;
    if (t < NT) {
        const int k = t;
        float mn = INFINITY, mxv = -INFINITY;
        float Apos = 0.f, Bpos = 0.f, Aneg = 0.f, Bneg = 0.f;
        for (int c = 0; c < CHUNKS; ++c) {
            const int o = k * CHUNKS + c;
            mn  = fminf(mn,  mmpart[o * 2 + 0]);
            mxv = fmaxf(mxv, mmpart[o * 2 + 1]);
            Apos += parts[o * 4 + 0];
            Bpos += parts[o * 4 + 1];
            Aneg += parts[o * 4 + 2];
            Bneg += parts[o * 4 + 3];
        }
        const float inv = 1.0f / (mxv - mn);
        // sum w*p2*(1-(M-mn)*inv) = A - inv*(B - mn*A)
        pos = Apos - inv * (Bpos - mn * Apos);
        neg = Aneg - inv * (Bneg - mn * Aneg);
    }
    sp[t] = pos; sn[t] = neg;
    __syncthreads();
    if (t == 0) {
        float P = 0.f, N = 0.f;
        for (int i = 0; i < NT; ++i) { P += sp[i]; N += sn[i]; }
        const float total = (P * 0.7f + N * 0.3f) * 2.0f;
        const int e = *epoch;
        const float la = (e < 100) ? (float)e : 100.0f;   // lambda_a_delta = 1
        *out = la * total;
    }
}

extern "C" void kernel_launch(void* const* d_in, const int* in_sizes, int n_in,
                              void* d_out, int out_size, void* d_ws, size_t ws_size,
                              hipStream_t stream)
{
    (void)in_sizes; (void)n_in; (void)out_size; (void)ws_size;
    const float* beta  = (const float*)d_in[0];
    const float* W     = (const float*)d_in[1];
    const int*   epoch = (const int*)d_in[2];
    float* out = (float*)d_out;

    char* ws = (char*)d_ws;
    int*   top_idx  = (int*)ws;    ws += NT * TOPN * sizeof(int);
    float* top_p    = (float*)ws;  ws += NT * TOPN * sizeof(float);
    float* rowstats = (float*)ws;  ws += NT * 2 * sizeof(float);
    float* mmpart   = (float*)ws;  ws += NT * CHUNKS * 2 * sizeof(float);
    float* parts    = (float*)ws;  ws += NT * CHUNKS * 4 * sizeof(float);

    topk_kernel<<<NT, 256, 0, stream>>>(beta, top_idx, top_p, rowstats);
    fused_kernel<<<NT * CHUNKS, 256, 0, stream>>>(beta, W, top_idx, top_p, rowstats, mmpart, parts);
    finalize_kernel<<<1, 128, 0, stream>>>(mmpart, parts, epoch, out);
}